// Round 1
// 517.194 us; speedup vs baseline: 1.1301x; 1.1301x over previous
//
#include <hip/hip_runtime.h>
#include <math.h>

typedef unsigned short u16;
typedef short bf16x8 __attribute__((ext_vector_type(8)));
typedef float f32x4 __attribute__((ext_vector_type(4)));

// Problem constants (B=2, S=4096, H=2048, NH=16, NKV=4, HD=128, g=1024)

__device__ __forceinline__ u16 f2bf(float x) {
  union { float f; unsigned u; } c; c.f = x;
  unsigned r = (c.u + 0x7FFFu + ((c.u >> 16) & 1u)) >> 16;  // RNE
  return (u16)r;
}
__device__ __forceinline__ float bf2f(u16 x) {
  union { unsigned u; float f; } c; c.u = ((unsigned)x) << 16;
  return c.f;
}

// async 16B global -> LDS (wave-uniform LDS base + lane*16)
#define GLD16(gp, lp)                                                   \
  __builtin_amdgcn_global_load_lds(                                     \
      (__attribute__((address_space(1))) void*)(gp),                    \
      (__attribute__((address_space(3))) void*)(lp), 16, 0, 0)

// ---------------------------------------------------------------------------
// fp32 -> bf16 elementwise cast (hidden_states)
// ---------------------------------------------------------------------------
__global__ __launch_bounds__(256) void cast_bf16_vec(
    const float* __restrict__ X, u16* __restrict__ Y) {
  const size_t i = ((size_t)blockIdx.x * 256 + threadIdx.x) * 4;
  float4 v = *(const float4*)(X + i);
  ushort4 o;
  o.x = f2bf(v.x); o.y = f2bf(v.y); o.z = f2bf(v.z); o.w = f2bf(v.w);
  *(ushort4*)(Y + i) = o;
}

// ---------------------------------------------------------------------------
// W (K x N fp32, row-major) -> Wt (N x K bf16, row-major). 64x64 LDS tiles.
// ---------------------------------------------------------------------------
__global__ __launch_bounds__(256) void wt_cast(
    const float* __restrict__ W, u16* __restrict__ Wt, int K, int N) {
  const int bk = blockIdx.y * 64;
  const int bn = blockIdx.x * 64;
  __shared__ float T[64 * 65];
  const int tid = threadIdx.x;
  #pragma unroll
  for (int u = 0; u < 16; ++u) {
    int idx = tid + u * 256;
    int kl = idx >> 6, nl = idx & 63;
    T[kl * 65 + nl] = W[(size_t)(bk + kl) * N + bn + nl];
  }
  __syncthreads();
  #pragma unroll
  for (int u = 0; u < 16; ++u) {
    int idx = tid + u * 256;
    int nl = idx >> 6, kl = idx & 63;
    Wt[(size_t)(bn + nl) * K + bk + kl] = f2bf(T[kl * 65 + nl]);
  }
}

// ---------------------------------------------------------------------------
// bf16 MFMA GEMM, 256x256 tile / 8-phase-style schedule (T1+T2+T3+T4+T5):
//   C[M,N] = A[M,K] @ Bt[N,K]^T
// 512 thr = 8 waves (2M x 4N), per-wave 128x64 output (8x4 16x16x32 frags).
// BK=32, ring of 4 LDS buffers (128 KiB), prefetch 2 K-tiles ahead,
// counted s_waitcnt vmcnt(4) once per K-tile (never a drain-to-0 in steady
// state), raw s_barrier (no implicit vmcnt drain), setprio(1) around MFMA.
// LDS XOR-swizzle (chunk ^= (row>>1)&3, 16B granules) applied to BOTH the
// global_load_lds *source* address (dest stays wave-linear) and the ds_read
// address -> A/B frag reads are 2-way (free) instead of 8-way conflicts.
// Buffer-reuse safety: tile t+2's loads target buf (t+2)&3 == (t-2)&3 whose
// reads completed >= 4 barriers earlier; memory-clobber asm fences at tile
// boundaries stop the compiler hoisting ds_reads past the vmcnt+barrier.
// Output: fp32 (Cf) or bf16 (Cb) - exactly one non-null.
// ---------------------------------------------------------------------------
__global__ __launch_bounds__(512) void gemm_bf16_256(
    const u16* __restrict__ A, const u16* __restrict__ Bt,
    float* __restrict__ Cf, u16* __restrict__ Cb, int M, int N, int K) {
  __shared__ u16 As[4][256 * 32];   // 64 KiB
  __shared__ u16 Bs[4][256 * 32];   // 64 KiB

  const int tid = threadIdx.x;

  // ---- T1: bijective XCD swizzle over linear tile index (m204 form) ----
  const int gridN = N >> 8;
  const int nwg = gridDim.x * gridDim.y;
  const int orig = blockIdx.y * gridDim.x + blockIdx.x;
  const int q8 = nwg >> 3, r8 = nwg & 7;
  const int xcd = orig & 7, lid = orig >> 3;
  const int wgid = (xcd < r8 ? xcd * (q8 + 1) : r8 * (q8 + 1) + (xcd - r8) * q8) + lid;
  const int bm = (wgid / gridN) << 8;
  const int bn = (wgid % gridN) << 8;

  const int w = tid >> 6, lane = tid & 63;
  const int col = lane & 15, quad = lane >> 4;
  const int wm = w >> 2, wn = w & 3;       // 2 x 4 wave grid
  const int sw = (col >> 1) & 3;           // read-side swizzle ((row>>1)&3 == (col>>1)&3)

  // ---- staging decomposition: 512 thr x 16B = 128 rows x 4 chunks/call ----
  const int srow = tid >> 2;               // 0..127
  const int scp  = tid & 3;                // dest chunk (linear for gload_lds)
  const int sc   = scp ^ ((srow >> 1) & 3);// swizzled SOURCE chunk (involution)

  const u16* Ag = A  + (size_t)bm * K;
  const u16* Bg = Bt + (size_t)bn * K;
  const u16* aS0 = Ag + (size_t)srow * K + sc * 8;
  const u16* aS1 = Ag + (size_t)(srow + 128) * K + sc * 8;   // (row+128>>1)&3 == (row>>1)&3
  const u16* bS0 = Bg + (size_t)srow * K + sc * 8;
  const u16* bS1 = Bg + (size_t)(srow + 128) * K + sc * 8;
  const int ldst0 = srow * 32 + scp * 8;
  const int ldst1 = (srow + 128) * 32 + scp * 8;

#define STAGE_A(t, buf) { GLD16(aS0 + (size_t)(t) * 32, &As[buf][ldst0]); \
                          GLD16(aS1 + (size_t)(t) * 32, &As[buf][ldst1]); }
#define STAGE_B(t, buf) { GLD16(bS0 + (size_t)(t) * 32, &Bs[buf][ldst0]); \
                          GLD16(bS1 + (size_t)(t) * 32, &Bs[buf][ldst1]); }

  f32x4 acc[8][4];
  #pragma unroll
  for (int i = 0; i < 8; ++i)
    #pragma unroll
    for (int j = 0; j < 4; ++j) acc[i][j] = (f32x4)(0.0f);

  const int NT = K >> 5;   // BK=32

  // ---- prologue: stage tiles 0 and 1, wait for tile 0 only ----
  STAGE_A(0, 0); STAGE_B(0, 0);
  if (NT > 1) {
    STAGE_A(1, 1); STAGE_B(1, 1);
    asm volatile("s_waitcnt vmcnt(4)" ::: "memory");
  } else {
    asm volatile("s_waitcnt vmcnt(0)" ::: "memory");
  }
  __builtin_amdgcn_s_barrier();
  asm volatile("" ::: "memory");

  // LDS frag read offsets (u16 units): row*32 + (quad^sw)*8
  const int aoff = (wm * 128 + col) * 32 + (quad ^ sw) * 8;
  const int boff = (wn * 64  + col) * 32 + (quad ^ sw) * 8;

  for (int t = 0; t < NT; ++t) {
    const int cur = t & 3;
    const bool pf = (t + 2 < NT);
    const int pbuf = (t + 2) & 3;

    // ================= phase A: m-frags 0..3, all 4 B-frags =================
    bf16x8 af[4], bfr[4];
    #pragma unroll
    for (int i = 0; i < 4; ++i)
      af[i] = *(const bf16x8*)&As[cur][aoff + (16 * i) * 32];
    #pragma unroll
    for (int j = 0; j < 4; ++j)
      bfr[j] = *(const bf16x8*)&Bs[cur][boff + (16 * j) * 32];
    if (pf) STAGE_A(t + 2, pbuf);
    __builtin_amdgcn_s_barrier();
    asm volatile("s_waitcnt lgkmcnt(0)");
    __builtin_amdgcn_s_setprio(1);
    #pragma unroll
    for (int i = 0; i < 4; ++i)
      #pragma unroll
      for (int j = 0; j < 4; ++j)
        acc[i][j] = __builtin_amdgcn_mfma_f32_16x16x32_bf16(af[i], bfr[j], acc[i][j], 0, 0, 0);
    __builtin_amdgcn_s_setprio(0);
    __builtin_amdgcn_s_barrier();

    // ================= phase B: m-frags 4..7 (B-frags persist) ==============
    bf16x8 af2[4];
    #pragma unroll
    for (int i = 0; i < 4; ++i)
      af2[i] = *(const bf16x8*)&As[cur][aoff + ((64 + 16 * i)) * 32];
    if (pf) STAGE_B(t + 2, pbuf);
    __builtin_amdgcn_s_barrier();
    asm volatile("s_waitcnt lgkmcnt(0)");
    __builtin_amdgcn_s_setprio(1);
    #pragma unroll
    for (int i = 0; i < 4; ++i)
      #pragma unroll
      for (int j = 0; j < 4; ++j)
        acc[4 + i][j] = __builtin_amdgcn_mfma_f32_16x16x32_bf16(af2[i], bfr[j], acc[4 + i][j], 0, 0, 0);
    __builtin_amdgcn_s_setprio(0);

    // ---- tile boundary: counted vmcnt (only this tile's 4 loads in flight)
    if (pf) asm volatile("s_waitcnt vmcnt(4)" ::: "memory");
    else    asm volatile("s_waitcnt vmcnt(0)" ::: "memory");
    __builtin_amdgcn_s_barrier();
    asm volatile("" ::: "memory");
  }

  // ---- epilogue: C/D layout col=lane&15, row=quad*4+reg [verified m89/m91]
  const int crow0 = bm + wm * 128 + quad * 4;
  const int ccol0 = bn + wn * 64 + col;
  #pragma unroll
  for (int i = 0; i < 8; ++i) {
    const int row0 = crow0 + 16 * i;
    #pragma unroll
    for (int j = 0; j < 4; ++j) {
      const int cc = ccol0 + 16 * j;
      #pragma unroll
      for (int r = 0; r < 4; ++r) {
        if (Cb) Cb[(size_t)(row0 + r) * N + cc] = f2bf(acc[i][j][r]);
        else    Cf[(size_t)(row0 + r) * N + cc] = acc[i][j][r];
      }
    }
  }
#undef STAGE_A
#undef STAGE_B
}

// ---------------------------------------------------------------------------
// Fused RoPE on the QKV buffer (8192 rows x 3072 cols bf16).
// head 0..15 = Q (cols h*128, gets 1/sqrt(128) folded in), 16..19 = K
// (cols 2048+(h-16)*128). One thread per (bs, head, d<64).
// ---------------------------------------------------------------------------
__global__ __launch_bounds__(256) void rope_qkv(
    u16* __restrict__ QKV, const int* __restrict__ pos) {
  const unsigned idx = blockIdx.x * 256 + threadIdx.x;
  const int d = idx & 63;
  const unsigned rest = idx >> 6;
  const int hh = rest % 20;
  const unsigned bs = rest / 20;

  const int colbase = (hh < 16) ? hh * 128 : 2048 + (hh - 16) * 128;
  u16* p = QKV + (size_t)bs * 3072 + colbase + d;
  const float x0 = bf2f(p[0]);
  const float x1 = bf2f(p[64]);
  const float t = (float)pos[bs];
  const float inv_freq = __expf((float)d * -0.14391156509676332f);  // ln(1e4)/64
  float s, c;
  __sincosf(t * inv_freq, &s, &c);
  const float sc = (hh < 16) ? 0.08838834764831845f : 1.0f;  // 1/sqrt(128) into Q
  p[0]  = f2bf((x0 * c - x1 * s) * sc);
  p[64] = f2bf((x1 * c + x0 * s) * sc);
}

// ---------------------------------------------------------------------------
// V columns of QKV (offset 2560, stride 3072) -> Vt (B, NKV, 128, S)
// ---------------------------------------------------------------------------
__global__ __launch_bounds__(256) void v_transpose(
    const u16* __restrict__ QKV, u16* __restrict__ Vt) {
  const int bid = blockIdx.x;
  const int st = bid & 63;
  const int kvh = (bid >> 6) & 3;
  const int b = bid >> 8;
  __shared__ u16 T[64 * 136];
  const int tid = threadIdx.x;
  #pragma unroll
  for (int u = 0; u < 4; ++u) {
    int idx = tid + u * 256;
    int sl = idx >> 4, ch = idx & 15;
    *(uint4*)&T[sl * 136 + ch * 8] =
        *(const uint4*)(QKV + ((size_t)(b * 4096 + st * 64 + sl)) * 3072 + 2560 + kvh * 128 + ch * 8);
  }
  __syncthreads();
  #pragma unroll
  for (int u = 0; u < 32; ++u) {
    int idx = tid + u * 256;
    int d = idx >> 6, sl = idx & 63;
    Vt[((size_t)((b * 4 + kvh) * 128 + d)) * 4096 + st * 64 + sl] = T[sl * 136 + d];
  }
}

// ---------------------------------------------------------------------------
// MFMA flash attention, max-free online softmax, S2-shift indexing.
// Block = 256 thr / 4 waves; 64-query tile of one (b,group,head); 64-key tiles.
// Wave w owns q-rows w*16..w*16+15. Q pre-scaled by 1/sqrt(128) in rope.
// LDS 45 KB -> 3 blocks/CU. 2 barriers per K-tile (Ps is wave-private).
// ---------------------------------------------------------------------------
__global__ __launch_bounds__(256) void attn_mfma(
    const u16* __restrict__ QKV, const u16* __restrict__ Vt,
    u16* __restrict__ Ob) {
  __shared__ u16 Ks[64 * 136];    // [key][128d]; also used to stage Q once
  __shared__ u16 Vs[128 * 72];    // [dim][64key]
  __shared__ u16 Ps[4][16 * 72];  // per-wave P [16q][64key]

  const int bid = blockIdx.x;
  const int qt = 15 - (bid & 15);           // heavy tiles first
  const int h  = (bid >> 4) & 15;
  const int gi = (bid >> 8) & 3;
  const int b  = bid >> 10;

  const int tid = threadIdx.x;
  const int w = tid >> 6, lane = tid & 63;
  const int col = lane & 15, quad = lane >> 4;

  const int shift = (h >= 8) ? 512 : 0;
  const int base_s = gi * 1024;
  const int kvh = h >> 2;

  // ---- stage Q tile through Ks, grab persistent A-frags ----
  const int sq0 = (base_s + qt * 64 + shift) & 4095;
  {
    const u16* qsrc = QKV + ((size_t)(b * 4096 + sq0)) * 3072 + h * 128;
    #pragma unroll
    for (int u = 0; u < 4; ++u) {
      int idx = tid + u * 256;
      int row = idx >> 4, ch = idx & 15;
      *(uint4*)&Ks[row * 136 + ch * 8] =
          *(const uint4*)(qsrc + (size_t)row * 3072 + ch * 8);
    }
  }
  __syncthreads();
  bf16x8 aq[4];  // A[m=col][k=quad*8+j] per 32-d chunk
  #pragma unroll
  for (int kk = 0; kk < 4; ++kk)
    aq[kk] = *(const bf16x8*)&Ks[(w * 16 + col) * 136 + kk * 32 + quad * 8];

  f32x4 o[8];
  #pragma unroll
  for (int jd = 0; jd < 8; ++jd) o[jd] = (f32x4)(0.0f);
  float lp[4] = {0.0f, 0.0f, 0.0f, 0.0f};  // per-lane partial denominators

  u16* Pw = &Ps[w][0];
  const int qrow_l = w * 16 + quad * 4;  // + r

  for (int kt = 0; kt <= qt; ++kt) {
    const int sk0 = (base_s + kt * 64 + shift) & 4095;
    __syncthreads();  // all waves done reading Ks/Vs (or aq frags on iter 0)
    {
      const u16* ksrc = QKV + ((size_t)(b * 4096 + sk0)) * 3072 + 2048 + kvh * 128;
      #pragma unroll
      for (int u = 0; u < 4; ++u) {
        int idx = tid + u * 256;
        int row = idx >> 4, ch = idx & 15;
        *(uint4*)&Ks[row * 136 + ch * 8] =
            *(const uint4*)(ksrc + (size_t)row * 3072 + ch * 8);
      }
      const u16* vsrc = Vt + ((size_t)((b * 4 + kvh) * 128)) * 4096 + sk0;
      #pragma unroll
      for (int u = 0; u < 4; ++u) {
        int idx = tid + u * 256;
        int d = idx >> 3, ch = idx & 7;
        *(uint4*)&Vs[d * 72 + ch * 8] =
            *(const uint4*)(vsrc + (size_t)d * 4096 + ch * 8);
      }
    }
    __syncthreads();

    // ---- S = Q K^T : 16 MFMA ----
    f32x4 sc[4];
    #pragma unroll
    for (int j = 0; j < 4; ++j) sc[j] = (f32x4)(0.0f);
    #pragma unroll
    for (int kk = 0; kk < 4; ++kk) {
      #pragma unroll
      for (int j = 0; j < 4; ++j) {
        bf16x8 bk = *(const bf16x8*)&Ks[(16 * j + col) * 136 + kk * 32 + quad * 8];
        sc[j] = __builtin_amdgcn_mfma_f32_16x16x32_bf16(aq[kk], bk, sc[j], 0, 0, 0);
      }
    }

    // ---- exp (no max subtraction; scores bounded), mask, P write, l accum ----
    #pragma unroll
    for (int j = 0; j < 4; ++j) {
      #pragma unroll
      for (int r = 0; r < 4; ++r) {
        float p = __expf(sc[j][r]);
        if (kt == qt && (16 * j + col) > (qrow_l + r)) p = 0.0f;
        lp[r] += p;
        Pw[(quad * 4 + r) * 72 + 16 * j + col] = f2bf(p);
      }
    }
    // Ps is wave-private: no barrier needed (in-wave ds ordering via lgkmcnt)

    // ---- O += P V : 16 MFMA ----
    #pragma unroll
    for (int ks = 0; ks < 2; ++ks) {
      bf16x8 ap = *(const bf16x8*)&Pw[col * 72 + ks * 32 + quad * 8];
      #pragma unroll
      for (int jd = 0; jd < 8; ++jd) {
        bf16x8 bv = *(const bf16x8*)&Vs[(16 * jd + col) * 72 + ks * 32 + quad * 8];
        o[jd] = __builtin_amdgcn_mfma_f32_16x16x32_bf16(ap, bv, o[jd], 0, 0, 0);
      }
    }
  }

  // ---- reduce denominators across the 16 col-lanes (same quad group) ----
  #pragma unroll
  for (int r = 0; r < 4; ++r) {
    lp[r] += __shfl_xor(lp[r], 1, 64);
    lp[r] += __shfl_xor(lp[r], 2, 64);
    lp[r] += __shfl_xor(lp[r], 4, 64);
    lp[r] += __shfl_xor(lp[r], 8, 64);
  }

  // ---- normalize + store (output lands at shifted seq pos = un-shift) ----
  #pragma unroll
  for (int r = 0; r < 4; ++r) {
    const int qg = qt * 64 + w * 16 + quad * 4 + r;
    const int sq = (base_s + qg + shift) & 4095;
    u16* dst = Ob + ((size_t)(b * 4096 + sq)) * 2048 + h * 128;
    const float inv = 1.0f / lp[r];
    #pragma unroll
    for (int jd = 0; jd < 8; ++jd)
      dst[16 * jd + col] = f2bf(o[jd][r] * inv);
  }
}

// ---------------------------------------------------------------------------
extern "C" void kernel_launch(void* const* d_in, const int* in_sizes, int n_in,
                              void* d_out, int out_size, void* d_ws, size_t ws_size,
                              hipStream_t stream) {
  const float* hs = (const float*)d_in[0];
  const int*   pos = (const int*)d_in[2];
  const float* Wq = (const float*)d_in[3];
  const float* Wk = (const float*)d_in[4];
  const float* Wv = (const float*)d_in[5];
  const float* Wo = (const float*)d_in[6];

  char* ws = (char*)d_ws;
  u16* hsb   = (u16*)ws; ws += (size_t)8192 * 2048 * 2;   // 33.5 MB
  u16* Wqkvt = (u16*)ws; ws += (size_t)3072 * 2048 * 2;   // 12.6 MB
  u16* Wot   = (u16*)ws; ws += (size_t)2048 * 2048 * 2;   //  8.4 MB
  u16* QKVb  = (u16*)ws; ws += (size_t)8192 * 3072 * 2;   // 50.3 MB
  u16* Vtt   = (u16*)ws; ws += (size_t)2 * 4 * 128 * 4096 * 2;  // 8.4 MB
  u16* Obh   = (u16*)ws; ws += (size_t)8192 * 2048 * 2;   // 33.5 MB

  dim3 blk(256);

  cast_bf16_vec<<<16384, blk, 0, stream>>>(hs, hsb);
  // Wqkvt rows: 0..2047 = Wq^T, 2048..2559 = Wk^T, 2560..3071 = Wv^T
  wt_cast<<<dim3(32, 32), blk, 0, stream>>>(Wq, Wqkvt, 2048, 2048);
  wt_cast<<<dim3(8, 32),  blk, 0, stream>>>(Wk, Wqkvt + (size_t)2048 * 2048, 2048, 512);
  wt_cast<<<dim3(8, 32),  blk, 0, stream>>>(Wv, Wqkvt + (size_t)2560 * 2048, 2048, 512);
  wt_cast<<<dim3(32, 32), blk, 0, stream>>>(Wo, Wot, 2048, 2048);

  // Fused QKV projection: (8192 x 2048) @ (3072 x 2048)^T -> 8192 x 3072 bf16
  gemm_bf16_256<<<dim3(12, 32), dim3(512), 0, stream>>>(hsb, Wqkvt, nullptr, QKVb, 8192, 3072, 2048);

  // Fused RoPE (Q scaled by 1/sqrt(128)): 8192 rows x 20 heads x 64 dim-pairs
  rope_qkv<<<40960, blk, 0, stream>>>(QKVb, pos);

  v_transpose<<<512, blk, 0, stream>>>(QKVb, Vtt);

  attn_mfma<<<2048, blk, 0, stream>>>(QKVb, Vtt, Obh);

  gemm_bf16_256<<<dim3(8, 32), dim3(512), 0, stream>>>(Obh, Wot, (float*)d_out, nullptr, 8192, 2048, 2048);
}

// Round 2
// 502.615 us; speedup vs baseline: 1.1629x; 1.0290x over previous
//
#include <hip/hip_runtime.h>
#include <math.h>

typedef unsigned short u16;
typedef short bf16x8 __attribute__((ext_vector_type(8)));
typedef float f32x4 __attribute__((ext_vector_type(4)));

// Problem constants (B=2, S=4096, H=2048, NH=16, NKV=4, HD=128, g=1024)

__device__ __forceinline__ u16 f2bf(float x) {
  union { float f; unsigned u; } c; c.f = x;
  unsigned r = (c.u + 0x7FFFu + ((c.u >> 16) & 1u)) >> 16;  // RNE
  return (u16)r;
}
__device__ __forceinline__ float bf2f(u16 x) {
  union { unsigned u; float f; } c; c.u = ((unsigned)x) << 16;
  return c.f;
}

// async 16B global -> LDS (wave-uniform LDS base + lane*16)
#define GLD16(gp, lp)                                                   \
  __builtin_amdgcn_global_load_lds(                                     \
      (__attribute__((address_space(1))) void*)(gp),                    \
      (__attribute__((address_space(3))) void*)(lp), 16, 0, 0)

// ---------------------------------------------------------------------------
// fp32 -> bf16 elementwise cast (hidden_states)
// ---------------------------------------------------------------------------
__global__ __launch_bounds__(256) void cast_bf16_vec(
    const float* __restrict__ X, u16* __restrict__ Y) {
  const size_t i = ((size_t)blockIdx.x * 256 + threadIdx.x) * 4;
  float4 v = *(const float4*)(X + i);
  ushort4 o;
  o.x = f2bf(v.x); o.y = f2bf(v.y); o.z = f2bf(v.z); o.w = f2bf(v.w);
  *(ushort4*)(Y + i) = o;
}

// ---------------------------------------------------------------------------
// W (K x N fp32, row-major) -> Wt (N x K bf16, row-major). 64x64 LDS tiles.
// ---------------------------------------------------------------------------
__global__ __launch_bounds__(256) void wt_cast(
    const float* __restrict__ W, u16* __restrict__ Wt, int K, int N) {
  const int bk = blockIdx.y * 64;
  const int bn = blockIdx.x * 64;
  __shared__ float T[64 * 65];
  const int tid = threadIdx.x;
  #pragma unroll
  for (int u = 0; u < 16; ++u) {
    int idx = tid + u * 256;
    int kl = idx >> 6, nl = idx & 63;
    T[kl * 65 + nl] = W[(size_t)(bk + kl) * N + bn + nl];
  }
  __syncthreads();
  #pragma unroll
  for (int u = 0; u < 16; ++u) {
    int idx = tid + u * 256;
    int nl = idx >> 6, kl = idx & 63;
    Wt[(size_t)(bn + nl) * K + bk + kl] = f2bf(T[kl * 65 + nl]);
  }
}

// ---------------------------------------------------------------------------
// bf16 MFMA GEMM, 256x256 tile / 8-phase-style schedule (T1+T2+T3+T4+T5):
//   C[M,N] = A[M,K] @ Bt[N,K]^T    (verified in round 1)
// ---------------------------------------------------------------------------
__global__ __launch_bounds__(512) void gemm_bf16_256(
    const u16* __restrict__ A, const u16* __restrict__ Bt,
    float* __restrict__ Cf, u16* __restrict__ Cb, int M, int N, int K) {
  __shared__ u16 As[4][256 * 32];   // 64 KiB
  __shared__ u16 Bs[4][256 * 32];   // 64 KiB

  const int tid = threadIdx.x;

  // ---- T1: bijective XCD swizzle over linear tile index (m204 form) ----
  const int gridN = N >> 8;
  const int nwg = gridDim.x * gridDim.y;
  const int orig = blockIdx.y * gridDim.x + blockIdx.x;
  const int q8 = nwg >> 3, r8 = nwg & 7;
  const int xcd = orig & 7, lid = orig >> 3;
  const int wgid = (xcd < r8 ? xcd * (q8 + 1) : r8 * (q8 + 1) + (xcd - r8) * q8) + lid;
  const int bm = (wgid / gridN) << 8;
  const int bn = (wgid % gridN) << 8;

  const int w = tid >> 6, lane = tid & 63;
  const int col = lane & 15, quad = lane >> 4;
  const int wm = w >> 2, wn = w & 3;       // 2 x 4 wave grid
  const int sw = (col >> 1) & 3;           // read-side swizzle ((row>>1)&3 == (col>>1)&3)

  // ---- staging decomposition: 512 thr x 16B = 128 rows x 4 chunks/call ----
  const int srow = tid >> 2;               // 0..127
  const int scp  = tid & 3;                // dest chunk (linear for gload_lds)
  const int sc   = scp ^ ((srow >> 1) & 3);// swizzled SOURCE chunk (involution)

  const u16* Ag = A  + (size_t)bm * K;
  const u16* Bg = Bt + (size_t)bn * K;
  const u16* aS0 = Ag + (size_t)srow * K + sc * 8;
  const u16* aS1 = Ag + (size_t)(srow + 128) * K + sc * 8;   // (row+128>>1)&3 == (row>>1)&3
  const u16* bS0 = Bg + (size_t)srow * K + sc * 8;
  const u16* bS1 = Bg + (size_t)(srow + 128) * K + sc * 8;
  const int ldst0 = srow * 32 + scp * 8;
  const int ldst1 = (srow + 128) * 32 + scp * 8;

#define STAGE_A(t, buf) { GLD16(aS0 + (size_t)(t) * 32, &As[buf][ldst0]); \
                          GLD16(aS1 + (size_t)(t) * 32, &As[buf][ldst1]); }
#define STAGE_B(t, buf) { GLD16(bS0 + (size_t)(t) * 32, &Bs[buf][ldst0]); \
                          GLD16(bS1 + (size_t)(t) * 32, &Bs[buf][ldst1]); }

  f32x4 acc[8][4];
  #pragma unroll
  for (int i = 0; i < 8; ++i)
    #pragma unroll
    for (int j = 0; j < 4; ++j) acc[i][j] = (f32x4)(0.0f);

  const int NT = K >> 5;   // BK=32

  // ---- prologue: stage tiles 0 and 1, wait for tile 0 only ----
  STAGE_A(0, 0); STAGE_B(0, 0);
  if (NT > 1) {
    STAGE_A(1, 1); STAGE_B(1, 1);
    asm volatile("s_waitcnt vmcnt(4)" ::: "memory");
  } else {
    asm volatile("s_waitcnt vmcnt(0)" ::: "memory");
  }
  __builtin_amdgcn_s_barrier();
  asm volatile("" ::: "memory");

  // LDS frag read offsets (u16 units): row*32 + (quad^sw)*8
  const int aoff = (wm * 128 + col) * 32 + (quad ^ sw) * 8;
  const int boff = (wn * 64  + col) * 32 + (quad ^ sw) * 8;

  for (int t = 0; t < NT; ++t) {
    const int cur = t & 3;
    const bool pf = (t + 2 < NT);
    const int pbuf = (t + 2) & 3;

    // ================= phase A: m-frags 0..3, all 4 B-frags =================
    bf16x8 af[4], bfr[4];
    #pragma unroll
    for (int i = 0; i < 4; ++i)
      af[i] = *(const bf16x8*)&As[cur][aoff + (16 * i) * 32];
    #pragma unroll
    for (int j = 0; j < 4; ++j)
      bfr[j] = *(const bf16x8*)&Bs[cur][boff + (16 * j) * 32];
    if (pf) STAGE_A(t + 2, pbuf);
    __builtin_amdgcn_s_barrier();
    asm volatile("s_waitcnt lgkmcnt(0)");
    __builtin_amdgcn_s_setprio(1);
    #pragma unroll
    for (int i = 0; i < 4; ++i)
      #pragma unroll
      for (int j = 0; j < 4; ++j)
        acc[i][j] = __builtin_amdgcn_mfma_f32_16x16x32_bf16(af[i], bfr[j], acc[i][j], 0, 0, 0);
    __builtin_amdgcn_s_setprio(0);
    __builtin_amdgcn_s_barrier();

    // ================= phase B: m-frags 4..7 (B-frags persist) ==============
    bf16x8 af2[4];
    #pragma unroll
    for (int i = 0; i < 4; ++i)
      af2[i] = *(const bf16x8*)&As[cur][aoff + ((64 + 16 * i)) * 32];
    if (pf) STAGE_B(t + 2, pbuf);
    __builtin_amdgcn_s_barrier();
    asm volatile("s_waitcnt lgkmcnt(0)");
    __builtin_amdgcn_s_setprio(1);
    #pragma unroll
    for (int i = 0; i < 4; ++i)
      #pragma unroll
      for (int j = 0; j < 4; ++j)
        acc[4 + i][j] = __builtin_amdgcn_mfma_f32_16x16x32_bf16(af2[i], bfr[j], acc[4 + i][j], 0, 0, 0);
    __builtin_amdgcn_s_setprio(0);

    // ---- tile boundary: counted vmcnt (only this tile's 4 loads in flight)
    if (pf) asm volatile("s_waitcnt vmcnt(4)" ::: "memory");
    else    asm volatile("s_waitcnt vmcnt(0)" ::: "memory");
    __builtin_amdgcn_s_barrier();
    asm volatile("" ::: "memory");
  }

  // ---- epilogue: C/D layout col=lane&15, row=quad*4+reg [verified m89/m91]
  const int crow0 = bm + wm * 128 + quad * 4;
  const int ccol0 = bn + wn * 64 + col;
  #pragma unroll
  for (int i = 0; i < 8; ++i) {
    const int row0 = crow0 + 16 * i;
    #pragma unroll
    for (int j = 0; j < 4; ++j) {
      const int cc = ccol0 + 16 * j;
      #pragma unroll
      for (int r = 0; r < 4; ++r) {
        if (Cb) Cb[(size_t)(row0 + r) * N + cc] = f2bf(acc[i][j][r]);
        else    Cf[(size_t)(row0 + r) * N + cc] = acc[i][j][r];
      }
    }
  }
#undef STAGE_A
#undef STAGE_B
}

// ---------------------------------------------------------------------------
// Fused RoPE on the QKV buffer (8192 rows x 3072 cols bf16).
// ---------------------------------------------------------------------------
__global__ __launch_bounds__(256) void rope_qkv(
    u16* __restrict__ QKV, const int* __restrict__ pos) {
  const unsigned idx = blockIdx.x * 256 + threadIdx.x;
  const int d = idx & 63;
  const unsigned rest = idx >> 6;
  const int hh = rest % 20;
  const unsigned bs = rest / 20;

  const int colbase = (hh < 16) ? hh * 128 : 2048 + (hh - 16) * 128;
  u16* p = QKV + (size_t)bs * 3072 + colbase + d;
  const float x0 = bf2f(p[0]);
  const float x1 = bf2f(p[64]);
  const float t = (float)pos[bs];
  const float inv_freq = __expf((float)d * -0.14391156509676332f);  // ln(1e4)/64
  float s, c;
  __sincosf(t * inv_freq, &s, &c);
  const float sc = (hh < 16) ? 0.08838834764831845f : 1.0f;  // 1/sqrt(128) into Q
  p[0]  = f2bf((x0 * c - x1 * s) * sc);
  p[64] = f2bf((x1 * c + x0 * s) * sc);
}

// ---------------------------------------------------------------------------
// V columns of QKV (offset 2560, stride 3072) -> Vt (B, NKV, 128, S)
// ---------------------------------------------------------------------------
__global__ __launch_bounds__(256) void v_transpose(
    const u16* __restrict__ QKV, u16* __restrict__ Vt) {
  const int bid = blockIdx.x;
  const int st = bid & 63;
  const int kvh = (bid >> 6) & 3;
  const int b = bid >> 8;
  __shared__ u16 T[64 * 136];
  const int tid = threadIdx.x;
  #pragma unroll
  for (int u = 0; u < 4; ++u) {
    int idx = tid + u * 256;
    int sl = idx >> 4, ch = idx & 15;
    *(uint4*)&T[sl * 136 + ch * 8] =
        *(const uint4*)(QKV + ((size_t)(b * 4096 + st * 64 + sl)) * 3072 + 2560 + kvh * 128 + ch * 8);
  }
  __syncthreads();
  #pragma unroll
  for (int u = 0; u < 32; ++u) {
    int idx = tid + u * 256;
    int d = idx >> 6, sl = idx & 63;
    Vt[((size_t)((b * 4 + kvh) * 128 + d)) * 4096 + st * 64 + sl] = T[sl * 136 + d];
  }
}

// ---------------------------------------------------------------------------
// MFMA flash attention, max-free online softmax, S2-shift indexing.
// v2: async global_load_lds staging, double-buffered K/V (unpadded, XOR-
// swizzled both-sides per rule #21), 1-deep prefetch with counted vmcnt(8),
// raw s_barrier (no implicit drain), setprio around MFMA clusters.
// LDS 73 KB -> 2 blocks/CU; loads fly under the full compute phase.
// Swizzle: LDS[row][chunk c] = GLOBAL[row][c ^ (row&7)] (16B chunks);
// all frag reads have row&7 == col&7, so read chunk = cg ^ (col&7).
// ---------------------------------------------------------------------------
__global__ __launch_bounds__(256) void attn_mfma(
    const u16* __restrict__ QKV, const u16* __restrict__ Vt,
    u16* __restrict__ Ob) {
  __shared__ u16 Ks[2][64 * 128];   // [key][128d] swizzled; buf0 stages Q first
  __shared__ u16 Vs[2][128 * 64];   // [dim][64key] swizzled
  __shared__ u16 Ps[4][16 * 72];    // per-wave P [16q][64key] (padded, ds_write path)

  const int bid = blockIdx.x;
  const int qt = 15 - (bid & 15);           // heavy tiles first
  const int h  = (bid >> 4) & 15;
  const int gi = (bid >> 8) & 3;
  const int b  = bid >> 10;

  const int tid = threadIdx.x;
  const int w = tid >> 6, lane = tid & 63;
  const int col = lane & 15, quad = lane >> 4;

  const int shift = (h >= 8) ? 512 : 0;
  const int base_s = gi * 1024;
  const int kvh = h >> 2;

  // ---- staging geometry: 256 thr x 16B x 4 rounds = 16 KB tile ----
  // K/Q tile rows are 256 B (16 chunks): row = (tid>>4)+u*16, chunk = tid&15
  // V tile rows are 128 B (8 chunks):    row = (tid>>3)+u*32, chunk = tid&7
  // source chunk = dest chunk ^ (row&7); (row&7) is u-invariant.
  const int kco8 = ((tid & 15) ^ ((tid >> 4) & 7)) << 3;   // u16 units
  const int vco8 = ((tid & 7) ^ ((tid >> 3) & 7)) << 3;
  const size_t krow = (size_t)(tid >> 4) * 3072 + kco8;
  const size_t vrow = (size_t)(tid >> 3) * 4096 + vco8;
  u16* kdst = &Ks[0][0] + tid * 8;   // + buf*8192 + u*2048 (lane-linear 16B)
  u16* vdst = &Vs[0][0] + tid * 8;
  const size_t vbase = (size_t)((b * 4 + kvh) * 128) * 4096;
  const u16* kgb = QKV + (size_t)b * 4096 * 3072 + 2048 + kvh * 128;

#define ASTAGE(kt_, buf_) {                                               \
    const int sk_ = (base_s + (kt_) * 64 + shift) & 4095;                 \
    const u16* ks_ = kgb + (size_t)sk_ * 3072;                            \
    const u16* vs_ = Vt + vbase + sk_;                                    \
    GLD16(ks_ + krow,             kdst + (buf_) * 8192);                  \
    GLD16(ks_ + krow + 16 * 3072, kdst + (buf_) * 8192 + 2048);           \
    GLD16(ks_ + krow + 32 * 3072, kdst + (buf_) * 8192 + 4096);           \
    GLD16(ks_ + krow + 48 * 3072, kdst + (buf_) * 8192 + 6144);           \
    GLD16(vs_ + vrow,             vdst + (buf_) * 8192);                  \
    GLD16(vs_ + vrow + 32 * 4096, vdst + (buf_) * 8192 + 2048);           \
    GLD16(vs_ + vrow + 64 * 4096, vdst + (buf_) * 8192 + 4096);           \
    GLD16(vs_ + vrow + 96 * 4096, vdst + (buf_) * 8192 + 6144);           \
  }

  // ---- stage Q tile through Ks[0] (async), grab persistent A-frags ----
  const int sq0 = (base_s + qt * 64 + shift) & 4095;
  {
    const u16* qsrc = QKV + ((size_t)(b * 4096 + sq0)) * 3072 + h * 128;
    GLD16(qsrc + krow,             kdst);
    GLD16(qsrc + krow + 16 * 3072, kdst + 2048);
    GLD16(qsrc + krow + 32 * 3072, kdst + 4096);
    GLD16(qsrc + krow + 48 * 3072, kdst + 6144);
  }
  asm volatile("s_waitcnt vmcnt(0)" ::: "memory");
  __builtin_amdgcn_s_barrier();
  asm volatile("" ::: "memory");

  const int cxor = col & 7;
  bf16x8 aq[4];  // A[m=col][k=kk*32+quad*8+j]
  {
    const int qr = w * 16 + col;   // qr&7 == col&7
    #pragma unroll
    for (int kk = 0; kk < 4; ++kk)
      aq[kk] = *(const bf16x8*)&Ks[0][qr * 128 + ((((kk << 2) + quad) ^ cxor) << 3)];
  }
  // aq must be resident before any wave's tile-0 DMA can overwrite Ks[0]
  asm volatile("s_waitcnt lgkmcnt(0)" ::: "memory");
  __builtin_amdgcn_s_barrier();
  asm volatile("" ::: "memory");

  ASTAGE(0, 0);

  f32x4 o[8];
  #pragma unroll
  for (int jd = 0; jd < 8; ++jd) o[jd] = (f32x4)(0.0f);
  float lp[4] = {0.0f, 0.0f, 0.0f, 0.0f};  // per-lane partial denominators

  u16* Pw = &Ps[w][0];
  const int qrow_l = w * 16 + quad * 4;  // + r

  for (int kt = 0; kt <= qt; ++kt) {
    const u16* Kc = &Ks[kt & 1][0];
    const u16* Vc = &Vs[kt & 1][0];
    const bool pf = (kt < qt);
    if (pf) ASTAGE(kt + 1, (kt + 1) & 1);            // fly under this tile's compute
    if (pf) asm volatile("s_waitcnt vmcnt(8)" ::: "memory");  // wait current, keep prefetch
    else    asm volatile("s_waitcnt vmcnt(0)" ::: "memory");
    __builtin_amdgcn_s_barrier();
    asm volatile("" ::: "memory");

    // ---- S = Q K^T : 16 MFMA ----
    f32x4 scv[4];
    #pragma unroll
    for (int j = 0; j < 4; ++j) scv[j] = (f32x4)(0.0f);
    __builtin_amdgcn_s_setprio(1);
    #pragma unroll
    for (int kk = 0; kk < 4; ++kk) {
      #pragma unroll
      for (int j = 0; j < 4; ++j) {
        bf16x8 bk = *(const bf16x8*)&Kc[(16 * j + col) * 128 + ((((kk << 2) + quad) ^ cxor) << 3)];
        scv[j] = __builtin_amdgcn_mfma_f32_16x16x32_bf16(aq[kk], bk, scv[j], 0, 0, 0);
      }
    }
    __builtin_amdgcn_s_setprio(0);

    // ---- exp (no max subtraction; scores bounded), mask, P write, l accum ----
    const bool last = (kt == qt);
    #pragma unroll
    for (int j = 0; j < 4; ++j) {
      #pragma unroll
      for (int r = 0; r < 4; ++r) {
        float p = __expf(scv[j][r]);
        if (last && (16 * j + col) > (qrow_l + r)) p = 0.0f;
        lp[r] += p;
        Pw[(quad * 4 + r) * 72 + 16 * j + col] = f2bf(p);
      }
    }
    // Ps is wave-private: no barrier needed (in-wave ds ordering via lgkmcnt)

    // ---- O += P V : 16 MFMA ----
    __builtin_amdgcn_s_setprio(1);
    #pragma unroll
    for (int ks = 0; ks < 2; ++ks) {
      bf16x8 ap = *(const bf16x8*)&Pw[col * 72 + ks * 32 + quad * 8];
      #pragma unroll
      for (int jd = 0; jd < 8; ++jd) {
        bf16x8 bv = *(const bf16x8*)&Vc[(16 * jd + col) * 64 + ((((ks << 2) + quad) ^ cxor) << 3)];
        o[jd] = __builtin_amdgcn_mfma_f32_16x16x32_bf16(ap, bv, o[jd], 0, 0, 0);
      }
    }
    __builtin_amdgcn_s_setprio(0);

    // all LDS reads above were consumed by MFMAs -> complete before barrier
    asm volatile("" ::: "memory");
    __builtin_amdgcn_s_barrier();
  }
#undef ASTAGE

  // ---- reduce denominators across the 16 col-lanes (same quad group) ----
  #pragma unroll
  for (int r = 0; r < 4; ++r) {
    lp[r] += __shfl_xor(lp[r], 1, 64);
    lp[r] += __shfl_xor(lp[r], 2, 64);
    lp[r] += __shfl_xor(lp[r], 4, 64);
    lp[r] += __shfl_xor(lp[r], 8, 64);
  }

  // ---- normalize + store (output lands at shifted seq pos = un-shift) ----
  #pragma unroll
  for (int r = 0; r < 4; ++r) {
    const int qg = qt * 64 + w * 16 + quad * 4 + r;
    const int sq = (base_s + qg + shift) & 4095;
    u16* dst = Ob + ((size_t)(b * 4096 + sq)) * 2048 + h * 128;
    const float inv = 1.0f / lp[r];
    #pragma unroll
    for (int jd = 0; jd < 8; ++jd)
      dst[16 * jd + col] = f2bf(o[jd][r] * inv);
  }
}

// ---------------------------------------------------------------------------
extern "C" void kernel_launch(void* const* d_in, const int* in_sizes, int n_in,
                              void* d_out, int out_size, void* d_ws, size_t ws_size,
                              hipStream_t stream) {
  const float* hs = (const float*)d_in[0];
  const int*   pos = (const int*)d_in[2];
  const float* Wq = (const float*)d_in[3];
  const float* Wk = (const float*)d_in[4];
  const float* Wv = (const float*)d_in[5];
  const float* Wo = (const float*)d_in[6];

  char* ws = (char*)d_ws;
  u16* hsb   = (u16*)ws; ws += (size_t)8192 * 2048 * 2;   // 33.5 MB
  u16* Wqkvt = (u16*)ws; ws += (size_t)3072 * 2048 * 2;   // 12.6 MB
  u16* Wot   = (u16*)ws; ws += (size_t)2048 * 2048 * 2;   //  8.4 MB
  u16* QKVb  = (u16*)ws; ws += (size_t)8192 * 3072 * 2;   // 50.3 MB
  u16* Vtt   = (u16*)ws; ws += (size_t)2 * 4 * 128 * 4096 * 2;  // 8.4 MB
  u16* Obh   = (u16*)ws; ws += (size_t)8192 * 2048 * 2;   // 33.5 MB

  dim3 blk(256);

  cast_bf16_vec<<<16384, blk, 0, stream>>>(hs, hsb);
  // Wqkvt rows: 0..2047 = Wq^T, 2048..2559 = Wk^T, 2560..3071 = Wv^T
  wt_cast<<<dim3(32, 32), blk, 0, stream>>>(Wq, Wqkvt, 2048, 2048);
  wt_cast<<<dim3(8, 32),  blk, 0, stream>>>(Wk, Wqkvt + (size_t)2048 * 2048, 2048, 512);
  wt_cast<<<dim3(8, 32),  blk, 0, stream>>>(Wv, Wqkvt + (size_t)2560 * 2048, 2048, 512);
  wt_cast<<<dim3(32, 32), blk, 0, stream>>>(Wo, Wot, 2048, 2048);

  // Fused QKV projection: (8192 x 2048) @ (3072 x 2048)^T -> 8192 x 3072 bf16
  gemm_bf16_256<<<dim3(12, 32), dim3(512), 0, stream>>>(hsb, Wqkvt, nullptr, QKVb, 8192, 3072, 2048);

  // Fused RoPE (Q scaled by 1/sqrt(128)): 8192 rows x 20 heads x 64 dim-pairs
  rope_qkv<<<40960, blk, 0, stream>>>(QKVb, pos);

  v_transpose<<<512, blk, 0, stream>>>(QKVb, Vtt);

  attn_mfma<<<2048, blk, 0, stream>>>(QKVb, Vtt, Obh);

  gemm_bf16_256<<<dim3(8, 32), dim3(512), 0, stream>>>(Obh, Wot, (float*)d_out, nullptr, 8192, 2048, 2048);
}